// Round 1
// 1471.924 us; speedup vs baseline: 1.3673x; 1.3673x over previous
//
#include <hip/hip_runtime.h>

#define B_ 4
#define C_ 384
#define H_ 224
#define W_ 224
#define HH_ 28
#define WW_ 28
#define NS_ 784   // superpixels per image (28*28)

// ---------- bf16 helpers (LDS compaction only; global I/O is fp32) ----------
__device__ __forceinline__ float bf2f(unsigned int u) {
    union { unsigned int i; float f; } v; v.i = u << 16; return v.f;
}
__device__ __forceinline__ unsigned int f2bf(float f) {
    union { float f; unsigned int i; } v; v.f = f;
    unsigned int x = v.i;
    return (x + 0x7FFFu + ((x >> 16) & 1u)) >> 16;
}

// ---------- K1: 8x8 mean pool: xs(B,C,H,W) fp32 -> sf(B,C,28,28) fp32 ----------
__global__ __launch_bounds__(256) void k_pool(const float* __restrict__ xs,
                                              float* __restrict__ sf) {
    int idx = blockIdx.x * 256 + threadIdx.x;
    if (idx >= B_ * C_ * HH_ * WW_) return;
    int j  = idx % WW_;
    int t1 = idx / WW_;
    int i  = t1 % HH_;
    int t2 = t1 / HH_;
    int c  = t2 % C_;
    int b  = t2 / C_;
    const float* p = xs + (((long)(b * C_ + c)) * H_ + i * 8) * (long)W_ + j * 8;
    float s = 0.f;
#pragma unroll
    for (int r = 0; r < 8; ++r) {
        float4 v0 = *(const float4*)(p + (long)r * W_);
        float4 v1 = *(const float4*)(p + (long)r * W_ + 4);
        s += v0.x + v0.y + v0.z + v0.w + v1.x + v1.y + v1.z + v1.w;
    }
    sf[idx] = s * (1.f / 64.f);
}

// ---------- K2a: affinity softmax + per-superpixel tap partials (NO atomics) ----------
// one block per (b, superpixel n), 512 threads.
// outputs: affG [b][n][64][9], stL [b][k][n][c], asumL [b][k][n]
__global__ __launch_bounds__(512) void k_aff2(const float* __restrict__ xs,
                                              const float* __restrict__ sf,
                                              float* __restrict__ affG,
                                              float* __restrict__ stL,
                                              float* __restrict__ asumL) {
    __shared__ unsigned int pixT32[C_ * 33];   // bf16 pixels [c][64], stride 66 u16 (50,688 B)
    __shared__ float4 smem4[864];              // 13,824 B: sf9 (phase1) -> redbuf+affL (later)
    float* smem2 = (float*)smem4;

    int t = threadIdx.x;
    int wg0 = blockIdx.x;
    int wg = (wg0 & 7) * 392 + (wg0 >> 3);     // XCD-chunked swizzle (3136 = 8*392)
    int b = wg / NS_, n = wg % NS_;
    int sa = n / WW_, sb = n % WW_;

    // ---- stage pixels: pixT32[c*33 + p/2] packs bf16(px p), bf16(px p+1) ----
    for (int e = t; e < C_ * 8; e += 512) {
        int c = e >> 3, r = e & 7;
        const float* g = xs + (((long)(b * C_ + c)) * H_ + sa * 8 + r) * (long)W_ + sb * 8;
        float4 v0 = *(const float4*)g;
        float4 v1 = *(const float4*)(g + 4);
        unsigned int* dst = pixT32 + c * 33 + r * 4;
        dst[0] = f2bf(v0.x) | (f2bf(v0.y) << 16);
        dst[1] = f2bf(v0.z) | (f2bf(v0.w) << 16);
        dst[2] = f2bf(v1.x) | (f2bf(v1.y) << 16);
        dst[3] = f2bf(v1.z) | (f2bf(v1.w) << 16);
    }
    // ---- stage sf9[c][k] fp32 (zero-padded out of range, matches reference) ----
    for (int e = t; e < C_ * 9; e += 512) {
        int c = e / 9, k = e - c * 9;
        int y = sa + k / 3 - 1, x = sb + (k % 3) - 1;
        float v = 0.f;
        if ((unsigned)y < HH_ && (unsigned)x < WW_)
            v = sf[(((long)(b * C_ + c)) * HH_ + y) * WW_ + x];
        smem2[e] = v;
    }
    __syncthreads();

    // ---- phase 1: logits. thread -> (pixel pair, c-slot); interleaved c partition
    //      keeps pix-read banks = lane mod 32 (conflict-free). ----
    int lane = t & 63, w = t >> 6;
    int px0 = (w & 3) * 16 + (lane & 7) * 2;          // even pixel index
    int s = ((w >> 2) << 3) + (lane >> 3);            // c-slot 0..15
    float acc0[9], acc1[9];
#pragma unroll
    for (int k = 0; k < 9; ++k) { acc0[k] = 0.f; acc1[k] = 0.f; }
    for (int cc = 0; cc < 24; ++cc) {
        int c = (s << 2) + (cc & 3) + ((cc >> 2) << 6);
        unsigned int pp = pixT32[c * 33 + (px0 >> 1)];
        float p0 = bf2f(pp & 0xffffu), p1 = bf2f(pp >> 16);
        const float* sr = smem2 + c * 9;
#pragma unroll
        for (int k = 0; k < 9; ++k) {
            float sv = sr[k];
            acc0[k] += p0 * sv;
            acc1[k] += p1 * sv;
        }
    }
#pragma unroll
    for (int k = 0; k < 9; ++k) {   // reduce over the 8 c-slots within the wave
        acc0[k] += __shfl_xor(acc0[k], 8);
        acc0[k] += __shfl_xor(acc0[k], 16);
        acc0[k] += __shfl_xor(acc0[k], 32);
        acc1[k] += __shfl_xor(acc1[k], 8);
        acc1[k] += __shfl_xor(acc1[k], 16);
        acc1[k] += __shfl_xor(acc1[k], 32);
    }
    __syncthreads();   // sf9 reads done; smem2 reusable

    float* redbuf = smem2;            // [2][64][9]  (two c-halves: w>>2)
    float* affL   = smem2 + 1152;     // [64][12]    (stride 12 -> b128-aligned reads)
    if ((lane >> 3) == 0) {
        int g = w >> 2;
#pragma unroll
        for (int k = 0; k < 9; ++k) {
            redbuf[g * 576 + px0 * 9 + k]       = acc0[k];
            redbuf[g * 576 + (px0 + 1) * 9 + k] = acc1[k];
        }
    }
    __syncthreads();

    // ---- phase 2: per-pixel softmax, one thread per pixel ----
    if (t < 64) {
        const float SCALE = 0.05103103630798288f;   // 384^-0.5
        float lg[9];
        float m = -1e30f;
#pragma unroll
        for (int k = 0; k < 9; ++k) {
            lg[k] = (redbuf[t * 9 + k] + redbuf[576 + t * 9 + k]) * SCALE;
            m = fmaxf(m, lg[k]);
        }
        float ssum = 0.f;
#pragma unroll
        for (int k = 0; k < 9; ++k) { lg[k] = __expf(lg[k] - m); ssum += lg[k]; }
        float inv = 1.f / ssum;
        float* ag = affG + (((long)(b * NS_ + n)) * 64 + t) * 9;
#pragma unroll
        for (int k = 0; k < 9; ++k) {
            float a = lg[k] * inv;
            affL[t * 12 + k] = a;
            ag[k] = a;
        }
    }
    __syncthreads();

    // ---- per-tap aff sums (consumed by k_asum gather) ----
    if (t < 9) {
        float ssum = 0.f;
        for (int px = 0; px < 64; ++px) ssum += affL[px * 12 + t];
        asumL[((long)(b * 9 + t)) * NS_ + n] = ssum;
    }

    // ---- phase 3: stL[b][k][n][c] = sum_p pix[p][c] * aff[p][k] ----
    if (t < C_) {
        int c = t;
        float a9[9];
#pragma unroll
        for (int k = 0; k < 9; ++k) a9[k] = 0.f;
        const float4* af4 = (const float4*)affL;
        for (int pp = 0; pp < 16; ++pp) {
            unsigned int u0 = pixT32[c * 33 + pp * 2];
            unsigned int u1 = pixT32[c * 33 + pp * 2 + 1];
            float q0 = bf2f(u0 & 0xffffu), q1 = bf2f(u0 >> 16);
            float q2 = bf2f(u1 & 0xffffu), q3 = bf2f(u1 >> 16);
            int px = pp * 4;
            {
                float4 a0 = af4[px * 3], a1 = af4[px * 3 + 1], a2 = af4[px * 3 + 2];
                a9[0] += q0 * a0.x; a9[1] += q0 * a0.y; a9[2] += q0 * a0.z; a9[3] += q0 * a0.w;
                a9[4] += q0 * a1.x; a9[5] += q0 * a1.y; a9[6] += q0 * a1.z; a9[7] += q0 * a1.w;
                a9[8] += q0 * a2.x;
            }
            {
                int p1i = px + 1;
                float4 a0 = af4[p1i * 3], a1 = af4[p1i * 3 + 1], a2 = af4[p1i * 3 + 2];
                a9[0] += q1 * a0.x; a9[1] += q1 * a0.y; a9[2] += q1 * a0.z; a9[3] += q1 * a0.w;
                a9[4] += q1 * a1.x; a9[5] += q1 * a1.y; a9[6] += q1 * a1.z; a9[7] += q1 * a1.w;
                a9[8] += q1 * a2.x;
            }
            {
                int p2i = px + 2;
                float4 a0 = af4[p2i * 3], a1 = af4[p2i * 3 + 1], a2 = af4[p2i * 3 + 2];
                a9[0] += q2 * a0.x; a9[1] += q2 * a0.y; a9[2] += q2 * a0.z; a9[3] += q2 * a0.w;
                a9[4] += q2 * a1.x; a9[5] += q2 * a1.y; a9[6] += q2 * a1.z; a9[7] += q2 * a1.w;
                a9[8] += q2 * a2.x;
            }
            {
                int p3i = px + 3;
                float4 a0 = af4[p3i * 3], a1 = af4[p3i * 3 + 1], a2 = af4[p3i * 3 + 2];
                a9[0] += q3 * a0.x; a9[1] += q3 * a0.y; a9[2] += q3 * a0.z; a9[3] += q3 * a0.w;
                a9[4] += q3 * a1.x; a9[5] += q3 * a1.y; a9[6] += q3 * a1.z; a9[7] += q3 * a1.w;
                a9[8] += q3 * a2.x;
            }
        }
        long base = ((long)b * 9 * NS_ + n) * (long)C_ + c;
#pragma unroll
        for (int k = 0; k < 9; ++k)
            stL[base + (long)k * (NS_ * C_)] = a9[k];
    }
}

// ---------- K2b-pre: gathered aff_sum denominators: asumD[b][n] ----------
__global__ __launch_bounds__(256) void k_asum(const float* __restrict__ asumL,
                                              float* __restrict__ asumD) {
    int idx = blockIdx.x * 256 + threadIdx.x;
    if (idx >= B_ * NS_) return;
    int b = idx / NS_, n = idx % NS_;
    int sa = n / WW_, sb = n % WW_;
    float s = 0.f;
#pragma unroll
    for (int i = 0; i < 3; ++i)
#pragma unroll
        for (int j = 0; j < 3; ++j) {
            int y = sa + 1 - i, x = sb + 1 - j;
            if ((unsigned)y < HH_ && (unsigned)x < WW_)
                s += asumL[((long)(b * 9 + i * 3 + j)) * NS_ + y * WW_ + x];
        }
    asumD[idx] = s;
}

// ---------- K2b: gather-fold + normalize: sft[b][c][n] = (sum taps) / (asumD+eps) ----------
// block per (b, y-row, 64-channel chunk): grid 4*28*6 = 672.
__global__ __launch_bounds__(256) void k_fold(const float* __restrict__ stL,
                                              const float* __restrict__ asumD,
                                              float* __restrict__ sft) {
    __shared__ float Ls[9 * 28 * 65];   // [tap=dyi*3+kxj][x'][cc], pad 65 (65,520 B)
    int t = threadIdx.x;
    int bid0 = blockIdx.x;
    int bid = (bid0 & 7) * 84 + (bid0 >> 3);   // XCD-chunked swizzle (672 = 8*84)
    int cch = bid % 6;
    int rest = bid / 6;
    int y = rest % 28, b = rest / 28;
    int c0 = cch * 64;

    for (int e4 = t; e4 < 9 * 28 * 16; e4 += 256) {
        int ccq = e4 & 15;
        int r2 = e4 >> 4;
        int xp = r2 % 28, tap = r2 / 28;
        int dyi = tap / 3, kxj = tap - dyi * 3;
        int k = (2 - dyi) * 3 + kxj;           // scatter tap k = (i=2-dyi, j=kxj)
        int row = y + dyi - 1;
        float4 v = make_float4(0.f, 0.f, 0.f, 0.f);
        if ((unsigned)row < HH_)
            v = *(const float4*)(stL + (((long)(b * 9 + k)) * NS_ + row * WW_ + xp) * (long)C_ + c0 + ccq * 4);
        float* d = Ls + (tap * 28 + xp) * 65 + ccq * 4;
        d[0] = v.x; d[1] = v.y; d[2] = v.z; d[3] = v.w;
    }
    __syncthreads();

    for (int e = t; e < 28 * 64; e += 256) {
        int x = e % 28, cc = e / 28;
        float num = 0.f;
#pragma unroll
        for (int dyi = 0; dyi < 3; ++dyi)
#pragma unroll
            for (int dxi = 0; dxi < 3; ++dxi) {
                int xp = x + dxi - 1;
                if ((unsigned)xp < WW_)
                    num += Ls[((dyi * 3 + (2 - dxi)) * 28 + xp) * 65 + cc];
            }
        float den = asumD[b * NS_ + y * WW_ + x] + 1e-12f;
        sft[((long)(b * C_ + c0 + cc)) * NS_ + y * WW_ + x] = num / den;
    }
}

// ---------- K4: GEMM  out[b,m,n] (or out[b,n,m] if trans) = sum_k W[m,k]*X[b,k,n] (+bias) ----------
// W fp32 (M,384), X fp32 (b,384,784). grid = b*(M/64)*13, block 256, 64x64 tile, 4x4/thread.
__global__ __launch_bounds__(256) void k_gemm(const float* __restrict__ Wg,
                                              const float* __restrict__ X,
                                              float* __restrict__ out,
                                              const float* __restrict__ bias,
                                              int M, int trans) {
    int nt = blockIdx.x % 13;
    int rest = blockIdx.x / 13;
    int Mt = M >> 6;
    int mt = rest % Mt, b = rest / Mt;
    int m0 = mt * 64, n0 = nt * 64;

    __shared__ float wL[16][64];
    __shared__ float xL[16][64];

    int t = threadIdx.x;
    int mi = t >> 4, ni = t & 15;
    float acc[4][4];
#pragma unroll
    for (int a = 0; a < 4; ++a)
#pragma unroll
        for (int c = 0; c < 4; ++c) acc[a][c] = 0.f;

    int wm = t >> 2, wk = (t & 3) * 4;

    for (int k0 = 0; k0 < 384; k0 += 16) {
        __syncthreads();
        {   // stage W tile, transposed into wL[k][m]
            const float* wp = Wg + (long)(m0 + wm) * 384 + k0 + wk;
            float4 v = *(const float4*)wp;
            wL[wk + 0][wm] = v.x;
            wL[wk + 1][wm] = v.y;
            wL[wk + 2][wm] = v.z;
            wL[wk + 3][wm] = v.w;
        }
#pragma unroll
        for (int i2 = 0; i2 < 4; ++i2) {   // stage X tile
            int e = t + i2 * 256;
            int kk = e >> 6, nn = e & 63;
            int n = n0 + nn;
            xL[kk][nn] = (n < NS_) ? X[((long)b * C_ + k0 + kk) * NS_ + n] : 0.f;
        }
        __syncthreads();
#pragma unroll
        for (int kk = 0; kk < 16; ++kk) {
            float wv[4], xv[4];
#pragma unroll
            for (int im = 0; im < 4; ++im) wv[im] = wL[kk][mi * 4 + im];
#pragma unroll
            for (int in = 0; in < 4; ++in) xv[in] = xL[kk][ni * 4 + in];
#pragma unroll
            for (int im = 0; im < 4; ++im)
#pragma unroll
                for (int in = 0; in < 4; ++in) acc[im][in] += wv[im] * xv[in];
        }
    }

#pragma unroll
    for (int im = 0; im < 4; ++im) {
        int m = m0 + mi * 4 + im;
        float bv = bias ? bias[m] : 0.f;
        if (!trans) {
            int n = n0 + ni * 4;
            if (n < NS_) {
                float4 v = make_float4(acc[im][0] + bv, acc[im][1] + bv,
                                       acc[im][2] + bv, acc[im][3] + bv);
                *(float4*)&out[((long)b * M + m) * NS_ + n] = v;
            }
        } else {
#pragma unroll
            for (int in = 0; in < 4; ++in) {
                int n = n0 + ni * 4 + in;
                if (n < NS_) out[((long)b * NS_ + n) * C_ + m] = acc[im][in] + bv;
            }
        }
    }
}

// ---------- K5: attention. grid = b*8*49, block 256. 16 queries per block. ----------
__global__ __launch_bounds__(256) void k_attn(const float* __restrict__ qkv,
                                              float* __restrict__ attno) {
    __shared__ float scL[16 * 785];    // scores [q][n], stride 785
    __shared__ float qL[48][16];
    __shared__ float kvT[48][32];
    __shared__ float red[16][17];
    __shared__ float mrow[16];
    __shared__ float linv[16];

    int t = threadIdx.x;
    int wgid = blockIdx.x;
    int qc = wgid % 49;
    int h  = (wgid / 49) & 7;
    int b  = wgid / (49 * 8);
    int q0 = qc * 16;
    const float* base = qkv + ((long)(b * 1152 + h * 144)) * NS_;

    for (int e = t; e < 768; e += 256) {   // stage Q
        int d = e >> 4, q = e & 15;
        qL[d][q] = base[(long)d * NS_ + q0 + q];
    }

    // pass 1: scores
    for (int kt0 = 0; kt0 < NS_; kt0 += 32) {
        __syncthreads();
        int kw = NS_ - kt0; if (kw > 32) kw = 32;
        for (int e = t; e < 48 * 32; e += 256) {
            int d = e >> 5, kk = e & 31;
            kvT[d][kk] = (kk < kw) ? base[(long)(48 + d) * NS_ + kt0 + kk] : 0.f;
        }
        __syncthreads();
#pragma unroll
        for (int it = 0; it < 2; ++it) {
            int item = t + it * 256;
            int q = item & 15, kk = item >> 4;
            if (kt0 + kk < NS_) {
                float a = 0.f;
#pragma unroll
                for (int d = 0; d < 48; ++d) a += qL[d][q] * kvT[d][kk];
                scL[q * 785 + kt0 + kk] = a * 0.14433756729740643f;   // 48^-0.5
            }
        }
    }
    __syncthreads();

    // softmax over keys (rows of scL)
    int q = t & 15, seg = t >> 4;
    {
        float m = -1e30f;
        for (int i = 0; i < 49; ++i) m = fmaxf(m, scL[q * 785 + seg * 49 + i]);
        red[q][seg] = m;
    }
    __syncthreads();
    if (t < 16) {
        float m = red[t][0];
        for (int i = 1; i < 16; ++i) m = fmaxf(m, red[t][i]);
        mrow[t] = m;
    }
    __syncthreads();
    {
        float mq = mrow[q];
        float s = 0.f;
        for (int i = 0; i < 49; ++i) {
            float e = __expf(scL[q * 785 + seg * 49 + i] - mq);
            scL[q * 785 + seg * 49 + i] = e;
            s += e;
        }
        red[q][seg] = s;
    }
    __syncthreads();
    if (t < 16) {
        float s = 0.f;
        for (int i = 0; i < 16; ++i) s += red[t][i];
        linv[t] = 1.f / s;
    }
    __syncthreads();

    // pass 2: PV
    float li = linv[q];
    int db = t >> 4;
    float acc0 = 0.f, acc1 = 0.f, acc2 = 0.f;
    for (int kt0 = 0; kt0 < NS_; kt0 += 32) {
        __syncthreads();
        int kw = NS_ - kt0; if (kw > 32) kw = 32;
        for (int e = t; e < 48 * 32; e += 256) {
            int d = e >> 5, kk = e & 31;
            kvT[d][kk] = (kk < kw) ? base[(long)(96 + d) * NS_ + kt0 + kk] : 0.f;
        }
        __syncthreads();
        for (int kk = 0; kk < kw; ++kk) {
            float p2 = scL[q * 785 + kt0 + kk];
            acc0 += p2 * kvT[db][kk];
            acc1 += p2 * kvT[db + 16][kk];
            acc2 += p2 * kvT[db + 32][kk];
        }
    }
    long ob = ((long)(b * C_ + h * 48)) * NS_ + q0 + q;
    attno[ob + (long)db * NS_]        = acc0 * li;
    attno[ob + (long)(db + 16) * NS_] = acc1 * li;
    attno[ob + (long)(db + 32) * NS_] = acc2 * li;
}

// ---------- K6: scatter refined super-tokens back to pixels; fp32 output ----------
// one block per (b, n). projo layout [b][n][c] (n-major, from trans GEMM).
__global__ __launch_bounds__(256) void k_scatter(const float* __restrict__ projo,
                                                 const float* __restrict__ affG,
                                                 float* __restrict__ out) {
    __shared__ float nbL[9][C_];
    __shared__ float affL[64 * 9];
    int t = threadIdx.x;
    int wg = blockIdx.x;
    int b  = wg / NS_, n = wg % NS_;
    int sa = n / WW_, sb = n % WW_;

    for (int e = t; e < 9 * C_; e += 256) {
        int k = e / C_, c = e - k * C_;
        int y = sa + k / 3 - 1, x = sb + (k % 3) - 1;
        nbL[k][c] = ((unsigned)y < HH_ && (unsigned)x < WW_)
                        ? projo[((long)(b * NS_ + y * WW_ + x)) * C_ + c] : 0.f;
    }
    for (int e = t; e < 576; e += 256)
        affL[e] = affG[((long)(b * NS_ + n)) * 576 + e];
    __syncthreads();

    int r = t & 7, cb = t >> 3;
    float ar[8][9];
#pragma unroll
    for (int s2 = 0; s2 < 8; ++s2)
#pragma unroll
        for (int k = 0; k < 9; ++k) ar[s2][k] = affL[(r * 8 + s2) * 9 + k];

    for (int cc = 0; cc < 12; ++cc) {
        int c = cb + cc * 32;
        float nb[9];
#pragma unroll
        for (int k = 0; k < 9; ++k) nb[k] = nbL[k][c];
        float ov[8];
#pragma unroll
        for (int s2 = 0; s2 < 8; ++s2) {
            float o = 0.f;
#pragma unroll
            for (int k = 0; k < 9; ++k) o += nb[k] * ar[s2][k];
            ov[s2] = o;
        }
        long ob = (((long)(b * C_ + c)) * H_ + sa * 8 + r) * (long)W_ + sb * 8;
        *(float4*)&out[ob]     = make_float4(ov[0], ov[1], ov[2], ov[3]);
        *(float4*)&out[ob + 4] = make_float4(ov[4], ov[5], ov[6], ov[7]);
    }
}

// ---------- scratch layout ----------
// d_ws (fp32 elems): only what the FINAL kernel needs (12.04 MB total)
#define WS_AFF   0L
#define WS_PROJ  1806336L
// d_out used as bulk fp32 scratch (77M floats available; all regions below are
// dead before k_scatter overwrites d_out with the final fp32 result)
#define DO_SF     0L
#define DO_SFT    1204224L
#define DO_QKV    2408448L
#define DO_ATTN   6021120L
#define DO_STL    7225344L     // [b][9][784][384] = 10,838,016 floats
#define DO_ASUML  18063360L    // [b][9][784]      = 28,224 floats
#define DO_ASUMD  18091584L    // [b][784]         = 3,136 floats

extern "C" void kernel_launch(void* const* d_in, const int* in_sizes, int n_in,
                              void* d_out, int out_size, void* d_ws, size_t ws_size,
                              hipStream_t stream) {
    const float* xs     = (const float*)d_in[0];
    const float* qkv_w  = (const float*)d_in[2];
    const float* proj_w = (const float*)d_in[3];
    const float* proj_b = (const float*)d_in[4];
    float* out = (float*)d_out;
    float* ws  = (float*)d_ws;
    float* osc = (float*)d_out;   // d_out as bulk scratch (308 MB >> 73 MB used)

    float* affG  = ws + WS_AFF;
    float* projo = ws + WS_PROJ;
    float* sf    = osc + DO_SF;
    float* sft   = osc + DO_SFT;
    float* qkvb  = osc + DO_QKV;
    float* attno = osc + DO_ATTN;
    float* stL   = osc + DO_STL;
    float* asumL = osc + DO_ASUML;
    float* asumD = osc + DO_ASUMD;

    k_pool<<<4704, 256, 0, stream>>>(xs, sf);
    k_aff2<<<B_ * NS_, 512, 0, stream>>>(xs, sf, affG, stL, asumL);
    k_asum<<<13, 256, 0, stream>>>(asumL, asumD);
    k_fold<<<4 * 28 * 6, 256, 0, stream>>>(stL, asumD, sft);
    k_gemm<<<4 * 18 * 13, 256, 0, stream>>>(qkv_w, sft, qkvb, nullptr, 1152, 0);
    k_attn<<<4 * 8 * 49, 256, 0, stream>>>(qkvb, attno);
    k_gemm<<<4 * 6 * 13, 256, 0, stream>>>(proj_w, attno, projo, proj_b, 384, 1);
    k_scatter<<<B_ * NS_, 256, 0, stream>>>(projo, affG, out);
}